// Round 5
// baseline (2004.719 us; speedup 1.0000x reference)
//
#include <hip/hip_runtime.h>
#include <hip/hip_bf16.h>
#include <cstdint>
#include <cstddef>

using fx4  = __attribute__((ext_vector_type(4))) float;

#define DEV __device__ __forceinline__

static constexpr int BATCH = 64;
static constexpr int NTOK  = 197;
static constexpr int NH    = 12;
static constexpr int HD    = 64;
static constexpr int MROWS = BATCH * NTOK;   // 12608
static constexpr int KDIM  = 768;

// ---------------------------------------------------------------------------
// DIAGNOSTIC pure-fp32 VALU GEMM: C[M,N] = A[M,K] @ B[N,K]^T
// 64x64 tile, 256 threads, 4x4 micro-tile/thread, BK=16.
// MODE 0: qkv epilogue (bias + scale, scatter q/k/v fp32 [B,H,N,hd])
// MODE 1: proj epilogue (+bias -> out fp32)
// ---------------------------------------------------------------------------
template<int NT, int MODE>
__global__ __launch_bounds__(256)
void gemm_f32_kernel(const float* __restrict__ A, const float* __restrict__ Bw,
                     const float* __restrict__ bias0, const float* __restrict__ bias1,
                     float* __restrict__ qf, float* __restrict__ kf,
                     float* __restrict__ vf, float* __restrict__ outp)
{
  __shared__ float As[16][68];
  __shared__ float Bs[16][68];

  const int t  = threadIdx.x;
  const int bm = blockIdx.x / NT, bn = blockIdx.x % NT;
  const int mload = t >> 2;        // 0..63
  const int kq    = (t & 3) * 4;   // 0,4,8,12
  const int tx = t & 15, ty = t >> 4;

  float acc[4][4] = {};

  const int arow = bm * 64 + mload;
  const bool aok = (arow < MROWS);
  const float* Aptr = A + (size_t)arow * KDIM + kq;
  const float* Bptr = Bw + (size_t)(bn * 64 + mload) * KDIM + kq;

  for (int kt = 0; kt < KDIM / 16; kt++) {
    fx4 av = aok ? *(const fx4*)(Aptr + kt * 16) : fx4{0.f, 0.f, 0.f, 0.f};
    fx4 bv = *(const fx4*)(Bptr + kt * 16);
    __syncthreads();
    As[kq + 0][mload] = av[0]; As[kq + 1][mload] = av[1];
    As[kq + 2][mload] = av[2]; As[kq + 3][mload] = av[3];
    Bs[kq + 0][mload] = bv[0]; Bs[kq + 1][mload] = bv[1];
    Bs[kq + 2][mload] = bv[2]; Bs[kq + 3][mload] = bv[3];
    __syncthreads();
    #pragma unroll
    for (int k = 0; k < 16; k++) {
      fx4 a4 = *(const fx4*)&As[k][ty * 4];
      fx4 b4 = *(const fx4*)&Bs[k][tx * 4];
      #pragma unroll
      for (int i = 0; i < 4; i++)
        #pragma unroll
        for (int j = 0; j < 4; j++)
          acc[i][j] += a4[i] * b4[j];
    }
  }

  #pragma unroll
  for (int i = 0; i < 4; i++) {
    int row = bm * 64 + ty * 4 + i;
    if (row >= MROWS) continue;
    #pragma unroll
    for (int j = 0; j < 4; j++) {
      int col = bn * 64 + tx * 4 + j;
      float v = acc[i][j];
      if (MODE == 0) {
        int which = col / 768;
        int hh = (col >> 6) % 12;   // 768 = 12*64
        int d  = col & 63;
        int b  = row / NTOK, n = row % NTOK;
        size_t o = (((size_t)(b * NH + hh)) * NTOK + n) * HD + d;
        if (which == 0)      qf[o] = (v + bias0[col]) * 0.125f;
        else if (which == 1) kf[o] = v;
        else                 vf[o] = v + bias1[col - 1536];
      } else {
        outp[(size_t)row * 768 + col] = v + bias0[col];
      }
    }
  }
}

// ---------------------------------------------------------------------------
// DIAGNOSTIC all-VALU fp32 attention, rpb computed inline from embeddings.
// 1 block = (b, h); 4 waves; wave w handles q-rows n = 4*ri + w.
// K staged in LDS (stride 65, conflict-free); scores: lane handles 4 keys
// (m = j*64 + lane); wave-wide shfl softmax; PV: lane = d, coalesced V reads.
// ---------------------------------------------------------------------------
__global__ __launch_bounds__(256)
void attn_diag_kernel(const float* __restrict__ qb, const float* __restrict__ kb,
                      const float* __restrict__ vf,
                      const float* __restrict__ rpbh, const float* __restrict__ rpbw,
                      const int* __restrict__ hidx, const int* __restrict__ widx,
                      float* __restrict__ of)
{
  __shared__ float Ks[NTOK * 65];   // 51220 B
  __shared__ float qs[4 * 64];
  __shared__ float ws[4 * 256];

  const int t = threadIdx.x, w = t >> 6, l = t & 63;
  const int bx = blockIdx.x;            // b*12 + h
  const int b = bx / 12, h = bx % 12;
  const size_t base = (size_t)bx * NTOK * HD;
  const float* qg = qb + base;
  const float* kg = kb + base;
  const float* vg = vf + base;

  for (int idx = t; idx < NTOK * HD; idx += 256)
    Ks[(idx >> 6) * 65 + (idx & 63)] = kg[idx];
  __syncthreads();

  for (int ri = 0; ri < 50; ri++) {
    int n = ri * 4 + w;
    if (n >= NTOK) continue;            // wave-uniform
    qs[w * 64 + l] = qg[(size_t)n * HD + l];
    __builtin_amdgcn_s_waitcnt(0);      // drain lgkm: qs visible wave-wide

    float sj[4];
    float mx = -1e30f;
    #pragma unroll
    for (int j = 0; j < 4; j++) {
      int m = j * 64 + l;
      float v = -1e30f;
      if (m < NTOK) {
        float acc = 0.f;
        #pragma unroll 8
        for (int d = 0; d < 64; d++) acc += qs[w * 64 + d] * Ks[m * 65 + d];
        int ij = n * NTOK + m;
        v = acc + rpbh[hidx[ij] * NH + h] + rpbw[widx[ij] * NH + h];
      }
      sj[j] = v; mx = fmaxf(mx, v);
    }
    #pragma unroll
    for (int off = 1; off < 64; off <<= 1) mx = fmaxf(mx, __shfl_xor(mx, off));
    float sum = 0.f;
    #pragma unroll
    for (int j = 0; j < 4; j++) {
      float e = (j * 64 + l < NTOK) ? __expf(sj[j] - mx) : 0.f;
      sj[j] = e; sum += e;
    }
    #pragma unroll
    for (int off = 1; off < 64; off <<= 1) sum += __shfl_xor(sum, off);
    float inv = 1.f / sum;
    #pragma unroll
    for (int j = 0; j < 4; j++) ws[w * 256 + j * 64 + l] = sj[j] * inv;
    __builtin_amdgcn_s_waitcnt(0);      // drain lgkm: ws visible wave-wide

    float o = 0.f;
    for (int m = 0; m < NTOK; m++) o += ws[w * 256 + m] * vg[(size_t)m * HD + l];
    of[((size_t)(b * NTOK + n)) * 768 + h * 64 + l] = o;
  }
}

// ---------------------------------------------------------------------------
extern "C" void kernel_launch(void* const* d_in, const int* in_sizes, int n_in,
                              void* d_out, int out_size, void* d_ws, size_t ws_size,
                              hipStream_t stream)
{
  const float* x      = (const float*)d_in[0];
  const float* qkv_w  = (const float*)d_in[1];
  const float* q_bias = (const float*)d_in[2];
  const float* v_bias = (const float*)d_in[3];
  const float* proj_w = (const float*)d_in[4];
  const float* proj_b = (const float*)d_in[5];
  const float* rpb_h  = (const float*)d_in[6];
  const float* rpb_w  = (const float*)d_in[7];
  const int*   h_idx  = (const int*)d_in[8];
  const int*   w_idx  = (const int*)d_in[9];
  float* out = (float*)d_out;

  char* ws = (char*)d_ws;
  size_t off = 0;
  auto alloc = [&](size_t bytes) { size_t o = off; off += (bytes + 255) & ~(size_t)255; return o; };

  const size_t QKV_ELEMS = (size_t)BATCH * NH * NTOK * HD;   // 9,682,944
  float* qfp = (float*)(ws + alloc(QKV_ELEMS * 4));
  float* kfp = (float*)(ws + alloc(QKV_ELEMS * 4));
  float* vfp = (float*)(ws + alloc(QKV_ELEMS * 4));
  float* ofp = (float*)(ws + alloc((size_t)MROWS * 768 * 4));
  (void)ws_size; (void)in_sizes; (void)n_in; (void)out_size;

  // 1) qkv GEMM (fp32 diagnostic): M=12608 (197 tiles of 64), N=2304 (36 tiles)
  gemm_f32_kernel<36, 0><<<197 * 36, 256, 0, stream>>>(
      x, qkv_w, q_bias, v_bias, qfp, kfp, vfp, nullptr);
  // 2) attention (fp32 diagnostic, rpb inline): 1 block per (b,h)
  attn_diag_kernel<<<BATCH * NH, 256, 0, stream>>>(
      qfp, kfp, vfp, rpb_h, rpb_w, h_idx, w_idx, ofp);
  // 3) proj GEMM (fp32 diagnostic): M=12608, N=768 (12 tiles)
  gemm_f32_kernel<12, 1><<<197 * 12, 256, 0, stream>>>(
      ofp, proj_w, proj_b, nullptr, nullptr, nullptr, nullptr, out);
}

// Round 6
// 756.007 us; speedup vs baseline: 2.6517x; 2.6517x over previous
//
#include <hip/hip_runtime.h>
#include <hip/hip_bf16.h>
#include <cstdint>
#include <cstddef>

using fx4  = __attribute__((ext_vector_type(4))) float;
using bfx8 = __attribute__((ext_vector_type(8))) short;
using sx4  = __attribute__((ext_vector_type(4))) short;

#define DEV __device__ __forceinline__

static constexpr int BATCH = 64;
static constexpr int NTOK  = 197;
static constexpr int NH    = 12;
static constexpr int HD    = 64;
static constexpr int MROWS = BATCH * NTOK;   // 12608
static constexpr int MPAD  = 12672;          // 99 * 128
static constexpr int KDIM  = 768;

DEV unsigned short f2bf(float f) {
  unsigned u = __builtin_bit_cast(unsigned, f);
  u += 0x7FFFu + ((u >> 16) & 1u);
  return (unsigned short)(u >> 16);
}
DEV float bf2f(unsigned short s) {
  unsigned u = ((unsigned)s) << 16;
  return __builtin_bit_cast(float, u);
}
DEV void split2(float x, short &hi, short &lo) {
  unsigned short h = f2bf(x);
  float r = x - bf2f(h);
  hi = (short)h;
  lo = (short)f2bf(r);
}

DEV void gload16(const unsigned short* g, unsigned short* l) {
  __builtin_amdgcn_global_load_lds(
      (const __attribute__((address_space(1))) unsigned int*)g,
      (__attribute__((address_space(3))) unsigned int*)l, 16, 0, 0);
}

// ---------------------------------------------------------------------------
// Elementwise fp32 -> (hi, lo) bf16 planes. Pads [nvec, nvec_pad) with zeros.
// ---------------------------------------------------------------------------
__global__ void split_kernel(const float* __restrict__ in,
                             unsigned short* __restrict__ hi,
                             unsigned short* __restrict__ lo,
                             int nvec, int nvec_pad)
{
  for (int v = blockIdx.x * 256 + threadIdx.x; v < nvec_pad; v += gridDim.x * 256) {
    fx4 x = (v < nvec) ? ((const fx4*)in)[v] : fx4{0.f, 0.f, 0.f, 0.f};
    sx4 h4, l4;
    #pragma unroll
    for (int q = 0; q < 4; q++) {
      short hh, ll;
      split2(x[q], hh, ll);
      h4[q] = hh; l4[q] = ll;
    }
    ((sx4*)hi)[v] = h4;
    ((sx4*)lo)[v] = l4;
  }
}

// ---------------------------------------------------------------------------
// Pure-bf16 MFMA GEMM over split planes: C = Ah.Bh^T + Ah.Bl^T + Al.Bh^T.
// K' = 3*768 = 2304, BK=32, 128x128 tile, 4 waves, global_load_lds staging.
// A padded to MPAD rows (no predication needed). B rows exact multiples of 128.
// MODE 0: qkv epilogue (bias + scale, scatter q/k/v fp32 [B,H,N,hd])
// MODE 1: proj epilogue (+bias -> out fp32)
// ---------------------------------------------------------------------------
template<int NT, int MODE>
__global__ __launch_bounds__(256, 2)
void gemm_bf16_kernel(const unsigned short* __restrict__ Ah, const unsigned short* __restrict__ Al,
                      const unsigned short* __restrict__ Bh, const unsigned short* __restrict__ Bl,
                      const float* __restrict__ bias0, const float* __restrict__ bias1,
                      float* __restrict__ qf, float* __restrict__ kf,
                      float* __restrict__ vf, float* __restrict__ outp)
{
  __shared__ unsigned short At[128 * 32];   // 8 KB, linear (gload dest)
  __shared__ unsigned short Bt[128 * 32];   // 8 KB

  const int t  = threadIdx.x;
  const int w  = t >> 6, l = t & 63;
  const int wr = w >> 1, wc = w & 1;
  const int fr = l & 15, g = l >> 4;
  const int bm = blockIdx.x / NT, bn = blockIdx.x % NT;

  const int r_issue = l >> 2;        // 0..15
  const int c_us    = (l & 3) * 8;   // 0,8,16,24

  fx4 acc[4][4];
  #pragma unroll
  for (int i = 0; i < 4; i++)
    #pragma unroll
    for (int j = 0; j < 4; j++) acc[i][j] = fx4{0.f, 0.f, 0.f, 0.f};

  #pragma unroll 1
  for (int kt = 0; kt < 72; kt++) {
    const int ph = kt / 24;
    const int k0 = (kt % 24) * 32;
    const unsigned short* Ap = (ph < 2) ? Ah : Al;
    const unsigned short* Bp = (ph == 0) ? Bh : (ph == 1 ? Bl : Bh);

    __syncthreads();   // previous compute done reading LDS
    #pragma unroll
    for (int e2 = 0; e2 < 2; e2++) {
      int e = w * 2 + e2;
      int arow = bm * 128 + e * 16 + r_issue;
      gload16(Ap + (size_t)arow * KDIM + k0 + c_us, &At[e * 512]);
      int brow = bn * 128 + e * 16 + r_issue;
      gload16(Bp + (size_t)brow * KDIM + k0 + c_us, &Bt[e * 512]);
    }
    __syncthreads();   // drains vmcnt: tile ready

    bfx8 fa[4], fb[4];
    #pragma unroll
    for (int i = 0; i < 4; i++)
      fa[i] = *(const bfx8*)&At[(wr * 64 + i * 16 + fr) * 32 + g * 8];
    #pragma unroll
    for (int j = 0; j < 4; j++)
      fb[j] = *(const bfx8*)&Bt[(wc * 64 + j * 16 + fr) * 32 + g * 8];
    #pragma unroll
    for (int i = 0; i < 4; i++)
      #pragma unroll
      for (int j = 0; j < 4; j++)
        acc[i][j] = __builtin_amdgcn_mfma_f32_16x16x32_bf16(fa[i], fb[j], acc[i][j], 0, 0, 0);
  }

  // epilogue: within frag, row = 4*(l>>4)+reg, col = l&15  (verified layout)
  #pragma unroll
  for (int i = 0; i < 4; i++) {
    #pragma unroll
    for (int j = 0; j < 4; j++) {
      #pragma unroll
      for (int r = 0; r < 4; r++) {
        int row = bm * 128 + wr * 64 + i * 16 + g * 4 + r;
        int col = bn * 128 + wc * 64 + j * 16 + fr;
        if (row >= MROWS) continue;
        float v = acc[i][j][r];
        if (MODE == 0) {
          int which = col / 768;
          int hh = (col >> 6) % 12;
          int d  = col & 63;
          int b  = row / NTOK, n = row % NTOK;
          size_t o = (((size_t)(b * NH + hh)) * NTOK + n) * HD + d;
          if (which == 0)      qf[o] = (v + bias0[col]) * 0.125f;
          else if (which == 1) kf[o] = v;
          else                 vf[o] = v + bias1[col - 1536];
        } else {
          outp[(size_t)row * 768 + col] = v + bias0[col];
        }
      }
    }
  }
}

// ---------------------------------------------------------------------------
// Blocked all-VALU fp32 attention (verified round-5 semantics, restructured).
// Block = (b, h, 64-row q-tile); 256 threads as 16x16; 4x4 microtile/thread.
// Scores: 4 phases of 64 keys (Q,K staged d-major in LDS); inline rpb lookup;
// 16-lane shfl softmax; P transposed to LDS; PV over 13 V-chunks of 16 keys.
// ---------------------------------------------------------------------------
__global__ __launch_bounds__(256)
void attn_v2_kernel(const float* __restrict__ qb, const float* __restrict__ kb,
                    const float* __restrict__ vf,
                    const float* __restrict__ rpbh, const float* __restrict__ rpbw,
                    const int* __restrict__ hidx, const int* __restrict__ widx,
                    float* __restrict__ of)
{
  __shared__ union {
    struct { float Qs[64][68]; float Ks[64][68]; } a;     // 34,816 B
    struct { float Pt[208][68]; float Vs[16][68]; } b;    // 60,928 B
  } u;

  const int t  = threadIdx.x;
  const int tx = t & 15, ty = t >> 4;
  const int bx = blockIdx.x;
  const int bh = bx >> 2, qt = bx & 3;
  const int b  = bh / NH, h = bh % NH;
  const size_t base = (size_t)bh * (NTOK * HD);
  const float* qg = qb + base;
  const float* kg = kb + base;
  const float* vg = vf + base;

  float acc[4][4][4];   // [phase][row i][key j] — all statically indexed

  // stage Q (64 rows x 64 d) d-major: Qs[d][row]
  #pragma unroll
  for (int rep = 0; rep < 4; rep++) {
    int idx = rep * 256 + t;
    int row = idx >> 4, d0 = (idx & 15) * 4;
    int gr = qt * 64 + row;
    fx4 v = (gr < NTOK) ? *(const fx4*)(qg + (size_t)gr * HD + d0) : fx4{0.f, 0.f, 0.f, 0.f};
    u.a.Qs[d0 + 0][row] = v[0]; u.a.Qs[d0 + 1][row] = v[1];
    u.a.Qs[d0 + 2][row] = v[2]; u.a.Qs[d0 + 3][row] = v[3];
  }

  // scores: 4 phases of 64 keys
  #pragma unroll 1
  for (int ph = 0; ph < 4; ph++) {
    __syncthreads();   // ph=0: Q staged (self), no prior K readers; ph>0: prev compute done
    #pragma unroll
    for (int rep = 0; rep < 4; rep++) {
      int idx = rep * 256 + t;
      int kk = idx >> 4, d0 = (idx & 15) * 4;
      int gk = ph * 64 + kk;
      fx4 v = (gk < NTOK) ? *(const fx4*)(kg + (size_t)gk * HD + d0) : fx4{0.f, 0.f, 0.f, 0.f};
      u.a.Ks[d0 + 0][kk] = v[0]; u.a.Ks[d0 + 1][kk] = v[1];
      u.a.Ks[d0 + 2][kk] = v[2]; u.a.Ks[d0 + 3][kk] = v[3];
    }
    __syncthreads();
    #pragma unroll
    for (int i = 0; i < 4; i++)
      #pragma unroll
      for (int j = 0; j < 4; j++) acc[ph][i][j] = 0.f;
    #pragma unroll 4
    for (int d = 0; d < 64; d++) {
      fx4 a4 = *(const fx4*)&u.a.Qs[d][ty * 4];
      fx4 b4 = *(const fx4*)&u.a.Ks[d][tx * 4];
      #pragma unroll
      for (int i = 0; i < 4; i++)
        #pragma unroll
        for (int j = 0; j < 4; j++)
          acc[ph][i][j] += a4[i] * b4[j];
    }
  }
  __syncthreads();   // all score reads of Qs/Ks complete (union reuse below)

  // rpb (inline, verified formula) + key mask
  const int qrow0 = qt * 64 + ty * 4;
  #pragma unroll
  for (int ph = 0; ph < 4; ph++) {
    #pragma unroll
    for (int j = 0; j < 4; j++) {
      int key = ph * 64 + tx * 4 + j;
      if (key < NTOK) {
        #pragma unroll
        for (int i = 0; i < 4; i++) {
          int qr = qrow0 + i; qr = qr > NTOK - 1 ? NTOK - 1 : qr;
          int ij = qr * NTOK + key;
          acc[ph][i][j] += rpbh[hidx[ij] * NH + h] + rpbw[widx[ij] * NH + h];
        }
      } else {
        #pragma unroll
        for (int i = 0; i < 4; i++) acc[ph][i][j] = -1e30f;
      }
    }
  }

  // softmax: row i lives across 16 tx lanes x 16 (ph,j) slots
  float inv_[4];
  #pragma unroll
  for (int i = 0; i < 4; i++) {
    float m = -1e30f;
    #pragma unroll
    for (int ph = 0; ph < 4; ph++)
      #pragma unroll
      for (int j = 0; j < 4; j++) m = fmaxf(m, acc[ph][i][j]);
    #pragma unroll
    for (int off = 1; off < 16; off <<= 1) m = fmaxf(m, __shfl_xor(m, off));
    float ssum = 0.f;
    #pragma unroll
    for (int ph = 0; ph < 4; ph++)
      #pragma unroll
      for (int j = 0; j < 4; j++) {
        float e = __expf(acc[ph][i][j] - m);
        acc[ph][i][j] = e; ssum += e;
      }
    #pragma unroll
    for (int off = 1; off < 16; off <<= 1) ssum += __shfl_xor(ssum, off);
    inv_[i] = 1.0f / ssum;
  }

  // write normalized P transposed: Pt[key][row]  (keys 197..207 are 0)
  #pragma unroll
  for (int ph = 0; ph < 4; ph++)
    #pragma unroll
    for (int j = 0; j < 4; j++) {
      int key = ph * 64 + tx * 4 + j;
      if (key < 208) {
        #pragma unroll
        for (int i = 0; i < 4; i++)
          u.b.Pt[key][ty * 4 + i] = acc[ph][i][j] * inv_[i];
      }
    }
  __syncthreads();

  // PV: 13 chunks of 16 keys
  fx4 oacc[4];
  #pragma unroll
  for (int i = 0; i < 4; i++) oacc[i] = fx4{0.f, 0.f, 0.f, 0.f};

  #pragma unroll 1
  for (int ch = 0; ch < 13; ch++) {
    {
      int row = t >> 4, d0 = (t & 15) * 4;
      int gk = ch * 16 + row;
      fx4 v = (gk < NTOK) ? *(const fx4*)(vg + (size_t)gk * HD + d0) : fx4{0.f, 0.f, 0.f, 0.f};
      *(fx4*)&u.b.Vs[row][d0] = v;
    }
    __syncthreads();
    #pragma unroll
    for (int m = 0; m < 16; m++) {
      fx4 p4 = *(const fx4*)&u.b.Pt[ch * 16 + m][ty * 4];
      fx4 v4 = *(const fx4*)&u.b.Vs[m][tx * 4];
      #pragma unroll
      for (int i = 0; i < 4; i++) oacc[i] += p4[i] * v4;
    }
    __syncthreads();   // accum done before next V overwrite
  }

  // out[b, qrow, h*64 + d]
  #pragma unroll
  for (int i = 0; i < 4; i++) {
    int qr = qt * 64 + ty * 4 + i;
    if (qr < NTOK)
      *(fx4*)&of[((size_t)(b * NTOK + qr)) * 768 + h * 64 + tx * 4] = oacc[i];
  }
}

// ---------------------------------------------------------------------------
extern "C" void kernel_launch(void* const* d_in, const int* in_sizes, int n_in,
                              void* d_out, int out_size, void* d_ws, size_t ws_size,
                              hipStream_t stream)
{
  const float* x      = (const float*)d_in[0];
  const float* qkv_w  = (const float*)d_in[1];
  const float* q_bias = (const float*)d_in[2];
  const float* v_bias = (const float*)d_in[3];
  const float* proj_w = (const float*)d_in[4];
  const float* proj_b = (const float*)d_in[5];
  const float* rpb_h  = (const float*)d_in[6];
  const float* rpb_w  = (const float*)d_in[7];
  const int*   h_idx  = (const int*)d_in[8];
  const int*   w_idx  = (const int*)d_in[9];
  float* out = (float*)d_out;

  char* ws = (char*)d_ws;
  size_t off = 0;
  auto alloc = [&](size_t bytes) { size_t o = off; off += (bytes + 255) & ~(size_t)255; return o; };

  const size_t QKV_ELEMS = (size_t)BATCH * NH * NTOK * HD;         // 9,682,944
  unsigned short* Axh = (unsigned short*)(ws + alloc((size_t)MPAD * KDIM * 2));
  unsigned short* Axl = (unsigned short*)(ws + alloc((size_t)MPAD * KDIM * 2));
  unsigned short* Bqh = (unsigned short*)(ws + alloc((size_t)2304 * KDIM * 2));
  unsigned short* Bql = (unsigned short*)(ws + alloc((size_t)2304 * KDIM * 2));
  unsigned short* Bph = (unsigned short*)(ws + alloc((size_t)768 * KDIM * 2));
  unsigned short* Bpl = (unsigned short*)(ws + alloc((size_t)768 * KDIM * 2));
  float* qfp = (float*)(ws + alloc(QKV_ELEMS * 4));
  float* kfp = (float*)(ws + alloc(QKV_ELEMS * 4));
  float* vfp = (float*)(ws + alloc(QKV_ELEMS * 4));
  float* ofp = (float*)(ws + alloc((size_t)MROWS * KDIM * 4));
  (void)ws_size; (void)in_sizes; (void)n_in; (void)out_size;

  const int nvec_x  = MROWS * KDIM / 4;
  const int nvec_xp = MPAD * KDIM / 4;

  // 1) split inputs into bf16 hi/lo planes
  split_kernel<<<2048, 256, 0, stream>>>(x, Axh, Axl, nvec_x, nvec_xp);
  split_kernel<<<1024, 256, 0, stream>>>(qkv_w, Bqh, Bql, 2304 * KDIM / 4, 2304 * KDIM / 4);
  split_kernel<<<512, 256, 0, stream>>>(proj_w, Bph, Bpl, 768 * KDIM / 4, 768 * KDIM / 4);
  // 2) qkv GEMM: 99 x 18 tiles
  gemm_bf16_kernel<18, 0><<<99 * 18, 256, 0, stream>>>(
      Axh, Axl, Bqh, Bql, q_bias, v_bias, qfp, kfp, vfp, nullptr);
  // 3) attention
  attn_v2_kernel<<<BATCH * NH * 4, 256, 0, stream>>>(
      qfp, kfp, vfp, rpb_h, rpb_w, h_idx, w_idx, ofp);
  // 4) split attention output, proj GEMM: 99 x 6 tiles
  split_kernel<<<2048, 256, 0, stream>>>(ofp, Axh, Axl, nvec_x, nvec_xp);
  gemm_bf16_kernel<6, 1><<<99 * 6, 256, 0, stream>>>(
      Axh, Axl, Bph, Bpl, proj_b, nullptr, nullptr, nullptr, nullptr, out);
}

// Round 7
// 488.059 us; speedup vs baseline: 4.1075x; 1.5490x over previous
//
#include <hip/hip_runtime.h>
#include <hip/hip_bf16.h>
#include <cstdint>
#include <cstddef>

using fx4  = __attribute__((ext_vector_type(4))) float;
using bfx8 = __attribute__((ext_vector_type(8))) short;
using sx4  = __attribute__((ext_vector_type(4))) short;

#define DEV __device__ __forceinline__

static constexpr int BATCH = 64;
static constexpr int NTOK  = 197;
static constexpr int NH    = 12;
static constexpr int HD    = 64;
static constexpr int MROWS = BATCH * NTOK;   // 12608
static constexpr int MPAD  = 12672;          // 99 * 128
static constexpr int KDIM  = 768;

DEV unsigned short f2bf(float f) {
  unsigned u = __builtin_bit_cast(unsigned, f);
  u += 0x7FFFu + ((u >> 16) & 1u);
  return (unsigned short)(u >> 16);
}
DEV float bf2f(unsigned short s) {
  unsigned u = ((unsigned)s) << 16;
  return __builtin_bit_cast(float, u);
}
DEV void split2(float x, short &hi, short &lo) {
  unsigned short h = f2bf(x);
  float r = x - bf2f(h);
  hi = (short)h;
  lo = (short)f2bf(r);
}

DEV void gload16(const unsigned short* g, unsigned short* l) {
  __builtin_amdgcn_global_load_lds(
      (const __attribute__((address_space(1))) unsigned int*)g,
      (__attribute__((address_space(3))) unsigned int*)l, 16, 0, 0);
}

// ---------------------------------------------------------------------------
// rpb[h][i][j] = rpb_high[h_index[i,j], h] + rpb_width[w_index[i,j], h]
// (same formula as the verified inline version of rounds 5/6)
// ---------------------------------------------------------------------------
__global__ void rpb_kernel(const float* __restrict__ rh, const float* __restrict__ rw,
                           const int* __restrict__ hidx, const int* __restrict__ widx,
                           float* __restrict__ rpb)
{
  int e = blockIdx.x * 256 + threadIdx.x;
  const int NN = NTOK * NTOK;
  if (e >= NH * NN) return;
  int h = e / NN, ij = e % NN;
  rpb[e] = rh[hidx[ij] * NH + h] + rw[widx[ij] * NH + h];
}

// ---------------------------------------------------------------------------
// Elementwise fp32 -> (hi, lo) bf16 planes. Pads [nvec, nvec_pad) with zeros.
// ---------------------------------------------------------------------------
__global__ void split_kernel(const float* __restrict__ in,
                             unsigned short* __restrict__ hi,
                             unsigned short* __restrict__ lo,
                             int nvec, int nvec_pad)
{
  for (int v = blockIdx.x * 256 + threadIdx.x; v < nvec_pad; v += gridDim.x * 256) {
    fx4 x = (v < nvec) ? ((const fx4*)in)[v] : fx4{0.f, 0.f, 0.f, 0.f};
    sx4 h4, l4;
    #pragma unroll
    for (int q = 0; q < 4; q++) {
      short hh, ll;
      split2(x[q], hh, ll);
      h4[q] = hh; l4[q] = ll;
    }
    ((sx4*)hi)[v] = h4;
    ((sx4*)lo)[v] = l4;
  }
}

// ---------------------------------------------------------------------------
// Pure-bf16 MFMA GEMM over split planes: C = Ah.Bh^T + Ah.Bl^T + Al.Bh^T.
// (verified rounds 5/6 pipeline)  K' = 3*768, BK=32, 128x128 tile, 4 waves.
// MODE 0: qkv epilogue (bias + scale, scatter q/k/v fp32 [B,H,N,hd])
// MODE 1: proj epilogue (+bias -> out fp32)
// ---------------------------------------------------------------------------
template<int NT, int MODE>
__global__ __launch_bounds__(256, 2)
void gemm_bf16_kernel(const unsigned short* __restrict__ Ah, const unsigned short* __restrict__ Al,
                      const unsigned short* __restrict__ Bh, const unsigned short* __restrict__ Bl,
                      const float* __restrict__ bias0, const float* __restrict__ bias1,
                      float* __restrict__ qf, float* __restrict__ kf,
                      float* __restrict__ vf, float* __restrict__ outp)
{
  __shared__ unsigned short At[128 * 32];
  __shared__ unsigned short Bt[128 * 32];

  const int t  = threadIdx.x;
  const int w  = t >> 6, l = t & 63;
  const int wr = w >> 1, wc = w & 1;
  const int fr = l & 15, g = l >> 4;
  const int bm = blockIdx.x / NT, bn = blockIdx.x % NT;

  const int r_issue = l >> 2;
  const int c_us    = (l & 3) * 8;

  fx4 acc[4][4];
  #pragma unroll
  for (int i = 0; i < 4; i++)
    #pragma unroll
    for (int j = 0; j < 4; j++) acc[i][j] = fx4{0.f, 0.f, 0.f, 0.f};

  #pragma unroll 1
  for (int kt = 0; kt < 72; kt++) {
    const int ph = kt / 24;
    const int k0 = (kt % 24) * 32;
    const unsigned short* Ap = (ph < 2) ? Ah : Al;
    const unsigned short* Bp = (ph == 0) ? Bh : (ph == 1 ? Bl : Bh);

    __syncthreads();
    #pragma unroll
    for (int e2 = 0; e2 < 2; e2++) {
      int e = w * 2 + e2;
      int arow = bm * 128 + e * 16 + r_issue;
      gload16(Ap + (size_t)arow * KDIM + k0 + c_us, &At[e * 512]);
      int brow = bn * 128 + e * 16 + r_issue;
      gload16(Bp + (size_t)brow * KDIM + k0 + c_us, &Bt[e * 512]);
    }
    __syncthreads();

    bfx8 fa[4], fb[4];
    #pragma unroll
    for (int i = 0; i < 4; i++)
      fa[i] = *(const bfx8*)&At[(wr * 64 + i * 16 + fr) * 32 + g * 8];
    #pragma unroll
    for (int j = 0; j < 4; j++)
      fb[j] = *(const bfx8*)&Bt[(wc * 64 + j * 16 + fr) * 32 + g * 8];
    #pragma unroll
    for (int i = 0; i < 4; i++)
      #pragma unroll
      for (int j = 0; j < 4; j++)
        acc[i][j] = __builtin_amdgcn_mfma_f32_16x16x32_bf16(fa[i], fb[j], acc[i][j], 0, 0, 0);
  }

  #pragma unroll
  for (int i = 0; i < 4; i++) {
    #pragma unroll
    for (int j = 0; j < 4; j++) {
      #pragma unroll
      for (int r = 0; r < 4; r++) {
        int row = bm * 128 + wr * 64 + i * 16 + g * 4 + r;
        int col = bn * 128 + wc * 64 + j * 16 + fr;
        if (row >= MROWS) continue;
        float v = acc[i][j][r];
        if (MODE == 0) {
          int which = col / 768;
          int hh = (col >> 6) % 12;
          int d  = col & 63;
          int b  = row / NTOK, n = row % NTOK;
          size_t o = (((size_t)(b * NH + hh)) * NTOK + n) * HD + d;
          if (which == 0)      qf[o] = (v + bias0[col]) * 0.125f;
          else if (which == 1) kf[o] = v;
          else                 vf[o] = v + bias1[col - 1536];
        } else {
          outp[(size_t)row * 768 + col] = v + bias0[col];
        }
      }
    }
  }
}

// ---------------------------------------------------------------------------
// MFMA attention. Block = (b, h, qt 64-row q-tile); 4 waves, wave w owns
// q-rows w*16..w*16+15 for BOTH QK^T and PV (softmax entirely within wave).
// bf16 q/k/P/V, fp32 softmax and MFMA accumulators. Verified MFMA layout:
// A-row=fr, k=g*8+e; C-row=g*4+r, C-col=fr.
// ---------------------------------------------------------------------------
__global__ __launch_bounds__(256)
void attn_mfma_kernel(const float* __restrict__ qf, const float* __restrict__ kf,
                      const float* __restrict__ vf, const float* __restrict__ rpb,
                      float* __restrict__ of)
{
  __shared__ union {
    struct { short Qb[64 * 72]; short Kb[224 * 72]; } s;   // 9216 + 32256 = 41472 B
    struct { short Pb[64 * 232]; short Vt[64 * 232]; } p;  // 29696 + 29696 = 59392 B
  } u;

  const int t  = threadIdx.x;
  const int w  = t >> 6, l = t & 63;
  const int fr = l & 15, g = l >> 4;
  const int bx = blockIdx.x;
  const int b  = bx / (NH * 4);
  const int h  = (bx / 4) % NH;
  const int qt = bx & 3;
  const size_t base = ((size_t)(b * NH + h)) * NTOK * HD;
  const float* qg = qf + base;
  const float* kg = kf + base;
  const float* vg = vf + base;
  const float* rhb = rpb + (size_t)h * (NTOK * NTOK);

  // ---- stage Q (64 rows) and K (224 rows, zero-padded) as bf16, stride 72
  {
    const int rr = t >> 3, c8 = (t & 7) * 8;
    #pragma unroll
    for (int p = 0; p < 2; p++) {
      int r = p * 32 + rr;
      int qrow = qt * 64 + r;
      fx4 a0 = fx4{0.f,0.f,0.f,0.f}, a1 = fx4{0.f,0.f,0.f,0.f};
      if (qrow < NTOK) {
        a0 = *(const fx4*)(qg + (size_t)qrow * HD + c8);
        a1 = *(const fx4*)(qg + (size_t)qrow * HD + c8 + 4);
      }
      bfx8 o8;
      #pragma unroll
      for (int q2 = 0; q2 < 4; q2++) {
        o8[q2]     = (short)f2bf(a0[q2]);
        o8[q2 + 4] = (short)f2bf(a1[q2]);
      }
      *(bfx8*)&u.s.Qb[r * 72 + c8] = o8;
    }
    #pragma unroll
    for (int p = 0; p < 7; p++) {
      int r = p * 32 + rr;
      fx4 a0 = fx4{0.f,0.f,0.f,0.f}, a1 = fx4{0.f,0.f,0.f,0.f};
      if (r < NTOK) {
        a0 = *(const fx4*)(kg + (size_t)r * HD + c8);
        a1 = *(const fx4*)(kg + (size_t)r * HD + c8 + 4);
      }
      bfx8 o8;
      #pragma unroll
      for (int q2 = 0; q2 < 4; q2++) {
        o8[q2]     = (short)f2bf(a0[q2]);
        o8[q2 + 4] = (short)f2bf(a1[q2]);
      }
      *(bfx8*)&u.s.Kb[r * 72 + c8] = o8;
    }
  }
  __syncthreads();

  // ---- QK^T: wave w, q-rows w*16+0..15, keys 0..223 (14 frags)
  bfx8 aq0 = *(const bfx8*)&u.s.Qb[(w * 16 + fr) * 72 + g * 8];
  bfx8 aq1 = *(const bfx8*)&u.s.Qb[(w * 16 + fr) * 72 + 32 + g * 8];
  fx4 sc[14];
  #pragma unroll
  for (int j = 0; j < 14; j++) sc[j] = fx4{0.f, 0.f, 0.f, 0.f};
  #pragma unroll
  for (int j = 0; j < 14; j++) {
    bfx8 k0 = *(const bfx8*)&u.s.Kb[(j * 16 + fr) * 72 + g * 8];
    bfx8 k1 = *(const bfx8*)&u.s.Kb[(j * 16 + fr) * 72 + 32 + g * 8];
    sc[j] = __builtin_amdgcn_mfma_f32_16x16x32_bf16(aq0, k0, sc[j], 0, 0, 0);
    sc[j] = __builtin_amdgcn_mfma_f32_16x16x32_bf16(aq1, k1, sc[j], 0, 0, 0);
  }

  // ---- rpb + key mask (element (g*4+r, fr): q-row w*16+g*4+r, key j*16+fr)
  #pragma unroll
  for (int j = 0; j < 14; j++) {
    int key = j * 16 + fr;
    if (key < NTOK) {
      #pragma unroll
      for (int r = 0; r < 4; r++) {
        int qrow = qt * 64 + w * 16 + g * 4 + r;
        if (qrow < NTOK) sc[j][r] += rhb[qrow * NTOK + key];
      }
    } else {
      #pragma unroll
      for (int r = 0; r < 4; r++) sc[j][r] = -1e30f;
    }
  }

  // ---- softmax per row (16-lane fr group); keep unnormalized exp, inv4[r]
  float inv4[4];
  #pragma unroll
  for (int r = 0; r < 4; r++) {
    float m = sc[0][r];
    #pragma unroll
    for (int j = 1; j < 14; j++) m = fmaxf(m, sc[j][r]);
    #pragma unroll
    for (int off = 1; off < 16; off <<= 1) m = fmaxf(m, __shfl_xor(m, off));
    float sum = 0.f;
    #pragma unroll
    for (int j = 0; j < 14; j++) {
      float e = __expf(sc[j][r] - m);
      sc[j][r] = e; sum += e;
    }
    #pragma unroll
    for (int off = 1; off < 16; off <<= 1) sum += __shfl_xor(sum, off);
    inv4[r] = 1.0f / sum;
  }

  __syncthreads();   // B1: all reads of Qb/Kb complete -> union reuse safe

  // ---- write P (unnormalized, bf16): Pb[qrow_local][key], stride 232
  #pragma unroll
  for (int j = 0; j < 14; j++) {
    int key = j * 16 + fr;
    #pragma unroll
    for (int r = 0; r < 4; r++)
      u.p.Pb[(w * 16 + g * 4 + r) * 232 + key] = (short)f2bf(sc[j][r]);
  }
  // ---- stage V transposed: Vt[d][m], bf16, stride 232 (m 0..223, zero-pad)
  #pragma unroll
  for (int rep = 0; rep < 14; rep++) {
    int task = rep * 256 + t;
    int m = task >> 4, dg = task & 15;
    fx4 v = (m < NTOK) ? *(const fx4*)(vg + (size_t)m * HD + dg * 4)
                       : fx4{0.f, 0.f, 0.f, 0.f};
    #pragma unroll
    for (int q2 = 0; q2 < 4; q2++)
      u.p.Vt[(dg * 4 + q2) * 232 + m] = (short)f2bf(v[q2]);
  }
  __syncthreads();   // B2: P and Vt fully staged

  // ---- PV: C2[q][d] = sum_m P[q][m] V[m][d]; A=Pb rows q, B=Vt rows d
  fx4 o2[4];
  #pragma unroll
  for (int j = 0; j < 4; j++) o2[j] = fx4{0.f, 0.f, 0.f, 0.f};
  #pragma unroll
  for (int kc = 0; kc < 7; kc++) {
    bfx8 pa = *(const bfx8*)&u.p.Pb[(w * 16 + fr) * 232 + kc * 32 + g * 8];
    #pragma unroll
    for (int j = 0; j < 4; j++) {
      bfx8 vb = *(const bfx8*)&u.p.Vt[(j * 16 + fr) * 232 + kc * 32 + g * 8];
      o2[j] = __builtin_amdgcn_mfma_f32_16x16x32_bf16(pa, vb, o2[j], 0, 0, 0);
    }
  }

  // ---- normalize + store: q-row w*16+g*4+r, d = j*16+fr
  #pragma unroll
  for (int r = 0; r < 4; r++) {
    int qrow = qt * 64 + w * 16 + g * 4 + r;
    if (qrow < NTOK) {
      float inv = inv4[r];
      #pragma unroll
      for (int j = 0; j < 4; j++)
        of[((size_t)(b * NTOK + qrow)) * 768 + h * 64 + j * 16 + fr] = o2[j][r] * inv;
    }
  }
}

// ---------------------------------------------------------------------------
extern "C" void kernel_launch(void* const* d_in, const int* in_sizes, int n_in,
                              void* d_out, int out_size, void* d_ws, size_t ws_size,
                              hipStream_t stream)
{
  const float* x      = (const float*)d_in[0];
  const float* qkv_w  = (const float*)d_in[1];
  const float* q_bias = (const float*)d_in[2];
  const float* v_bias = (const float*)d_in[3];
  const float* proj_w = (const float*)d_in[4];
  const float* proj_b = (const float*)d_in[5];
  const float* rpb_h  = (const float*)d_in[6];
  const float* rpb_w  = (const float*)d_in[7];
  const int*   h_idx  = (const int*)d_in[8];
  const int*   w_idx  = (const int*)d_in[9];
  float* out = (float*)d_out;

  char* ws = (char*)d_ws;
  size_t off = 0;
  auto alloc = [&](size_t bytes) { size_t o = off; off += (bytes + 255) & ~(size_t)255; return o; };

  const size_t QKV_ELEMS = (size_t)BATCH * NH * NTOK * HD;
  unsigned short* Axh = (unsigned short*)(ws + alloc((size_t)MPAD * KDIM * 2));
  unsigned short* Axl = (unsigned short*)(ws + alloc((size_t)MPAD * KDIM * 2));
  unsigned short* Bqh = (unsigned short*)(ws + alloc((size_t)2304 * KDIM * 2));
  unsigned short* Bql = (unsigned short*)(ws + alloc((size_t)2304 * KDIM * 2));
  unsigned short* Bph = (unsigned short*)(ws + alloc((size_t)768 * KDIM * 2));
  unsigned short* Bpl = (unsigned short*)(ws + alloc((size_t)768 * KDIM * 2));
  float* qfp = (float*)(ws + alloc(QKV_ELEMS * 4));
  float* kfp = (float*)(ws + alloc(QKV_ELEMS * 4));
  float* vfp = (float*)(ws + alloc(QKV_ELEMS * 4));
  float* rpb = (float*)(ws + alloc((size_t)NH * NTOK * NTOK * 4));
  float* ofp = (float*)(ws + alloc((size_t)MROWS * KDIM * 4));
  (void)ws_size; (void)in_sizes; (void)n_in; (void)out_size;

  const int nvec_x  = MROWS * KDIM / 4;
  const int nvec_xp = MPAD * KDIM / 4;

  // 1) split inputs into bf16 hi/lo planes; rpb table
  split_kernel<<<2048, 256, 0, stream>>>(x, Axh, Axl, nvec_x, nvec_xp);
  split_kernel<<<1024, 256, 0, stream>>>(qkv_w, Bqh, Bql, 2304 * KDIM / 4, 2304 * KDIM / 4);
  split_kernel<<<512, 256, 0, stream>>>(proj_w, Bph, Bpl, 768 * KDIM / 4, 768 * KDIM / 4);
  {
    int total = NH * NTOK * NTOK;
    rpb_kernel<<<(total + 255) / 256, 256, 0, stream>>>(rpb_h, rpb_w, h_idx, w_idx, rpb);
  }
  // 2) qkv GEMM: 99 x 18 tiles
  gemm_bf16_kernel<18, 0><<<99 * 18, 256, 0, stream>>>(
      Axh, Axl, Bqh, Bql, q_bias, v_bias, qfp, kfp, vfp, nullptr);
  // 3) MFMA attention
  attn_mfma_kernel<<<BATCH * NH * 4, 256, 0, stream>>>(qfp, kfp, vfp, rpb, ofp);
  // 4) split attention output, proj GEMM: 99 x 6 tiles
  split_kernel<<<2048, 256, 0, stream>>>(ofp, Axh, Axl, nvec_x, nvec_xp);
  gemm_bf16_kernel<6, 1><<<99 * 6, 256, 0, stream>>>(
      Axh, Axl, Bph, Bpl, proj_b, nullptr, nullptr, nullptr, nullptr, out);
}